// Round 1
// baseline (291.808 us; speedup 1.0000x reference)
//
#include <hip/hip_runtime.h>

typedef __bf16 bf16x8 __attribute__((ext_vector_type(8)));
typedef float f32x4 __attribute__((ext_vector_type(4)));

__device__ __forceinline__ unsigned short f2bf(float f) {
  union { float f; unsigned u; } x; x.f = f;
  unsigned u = x.u;
  unsigned r = (u + 0x7fffu + ((u >> 16) & 1u)) >> 16;  // RNE
  return (unsigned short)r;
}
__device__ __forceinline__ int pk2(float a, float b) {
  return (int)f2bf(a) | ((int)f2bf(b) << 16);
}

// C = A @ W^T + bias.  A: [8192 x 1024] (fp32 if AMODE==0, bf16 if AMODE==1).
// W: [1024 x 1024] fp32 row-major (nn.Linear layout: row n = output col n).
// OMODE 0: bf16 out [B,H,S,HD]; 1: bf16 out [B,H,HD,S]; 2: fp32 out [M,N].
template <int AMODE, int OMODE>
__global__ __launch_bounds__(256) void gemm_k(const void* __restrict__ A,
                                              const float* __restrict__ W,
                                              const float* __restrict__ bias,
                                              void* __restrict__ Out) {
  constexpr int K = 1024;
  __shared__ char lA[128 * 128];  // 128 rows x 64 bf16 (128B), XOR-swizzled
  __shared__ char lB[128 * 128];
  const int t = threadIdx.x;
  const int l = t & 63;
  const int w = t >> 6;
  const int wr = w >> 1, wc = w & 1;
  const int m0 = blockIdx.x * 128;
  const int n0 = blockIdx.y * 128;
  f32x4 acc[4][4];
#pragma unroll
  for (int i = 0; i < 4; ++i)
#pragma unroll
    for (int j = 0; j < 4; ++j) acc[i][j] = (f32x4){0.f, 0.f, 0.f, 0.f};

  for (int k0 = 0; k0 < K; k0 += 64) {
#pragma unroll
    for (int qq = 0; qq < 4; ++qq) {
      const int L = t * 8 + qq * 2048;
      const int r = L >> 6, c = L & 63;
      const int dst = r * 128 + ((c * 2) ^ ((r & 7) << 4));
      if constexpr (AMODE == 0) {
        const float* s0 = (const float*)A + (size_t)(m0 + r) * K + k0 + c;
        float4 f0 = *(const float4*)s0;
        float4 f1 = *(const float4*)(s0 + 4);
        int4 v;
        v.x = pk2(f0.x, f0.y); v.y = pk2(f0.z, f0.w);
        v.z = pk2(f1.x, f1.y); v.w = pk2(f1.z, f1.w);
        *(int4*)(lA + dst) = v;
      } else {
        const unsigned short* s0 =
            (const unsigned short*)A + (size_t)(m0 + r) * K + k0 + c;
        *(int4*)(lA + dst) = *(const int4*)s0;
      }
      const float* s1 = W + (size_t)(n0 + r) * K + k0 + c;
      float4 g0 = *(const float4*)s1;
      float4 g1 = *(const float4*)(s1 + 4);
      int4 u;
      u.x = pk2(g0.x, g0.y); u.y = pk2(g0.z, g0.w);
      u.z = pk2(g1.x, g1.y); u.w = pk2(g1.z, g1.w);
      *(int4*)(lB + dst) = u;
    }
    __syncthreads();
#pragma unroll
    for (int ks = 0; ks < 2; ++ks) {
      const int kb = ks * 64 + ((l >> 4) << 4);
      bf16x8 af[4], bfv[4];
#pragma unroll
      for (int i = 0; i < 4; ++i) {
        const int row = wr * 64 + i * 16 + (l & 15);
        af[i] = *(const bf16x8*)(lA + row * 128 + (kb ^ ((row & 7) << 4)));
      }
#pragma unroll
      for (int j = 0; j < 4; ++j) {
        const int row = wc * 64 + j * 16 + (l & 15);
        bfv[j] = *(const bf16x8*)(lB + row * 128 + (kb ^ ((row & 7) << 4)));
      }
#pragma unroll
      for (int i = 0; i < 4; ++i)
#pragma unroll
        for (int j = 0; j < 4; ++j)
          acc[i][j] = __builtin_amdgcn_mfma_f32_16x16x32_bf16(af[i], bfv[j],
                                                              acc[i][j], 0, 0, 0);
    }
    __syncthreads();
  }
  // epilogue: D frag layout: row=(l>>4)*4+rg, col=l&15
#pragma unroll
  for (int i = 0; i < 4; ++i)
#pragma unroll
    for (int j = 0; j < 4; ++j)
#pragma unroll
      for (int rg = 0; rg < 4; ++rg) {
        const int gm = m0 + wr * 64 + i * 16 + ((l >> 4) << 2) + rg;
        const int gn = n0 + wc * 64 + j * 16 + (l & 15);
        const float v = acc[i][j][rg] + bias[gn];
        if constexpr (OMODE == 0) {
          const int b = gm >> 11, s = gm & 2047, h = gn >> 6, hd = gn & 63;
          ((unsigned short*)Out)[((((size_t)(b * 16 + h)) * 2048 + s) << 6) + hd] =
              f2bf(v);
        } else if constexpr (OMODE == 1) {
          const int b = gm >> 11, s = gm & 2047, h = gn >> 6, hd = gn & 63;
          ((unsigned short*)Out)[((((size_t)(b * 16 + h)) << 6) + hd) * 2048 + s] =
              f2bf(v);
        } else {
          ((float*)Out)[(size_t)gm * 1024 + gn] = v;
        }
      }
}

// Flash attention, causal. qh/kh: [B,H,S,HD] bf16. vth: [B,H,HD,S] bf16.
// out: [B,S,D] bf16. Block = 256 thr (4 waves x 16 q-rows), KV-block = 64.
__global__ __launch_bounds__(256) void attn_k(const unsigned short* __restrict__ qh,
                                              const unsigned short* __restrict__ kh,
                                              const unsigned short* __restrict__ vth,
                                              unsigned short* __restrict__ out) {
  const int bh = blockIdx.x;       // b*16 + h
  const int q0 = blockIdx.y * 64;  // q-tile start
  const int t = threadIdx.x, l = t & 63, wv = t >> 6;
  __shared__ char lq[64 * 128];
  __shared__ char lk[64 * 128];
  __shared__ char lv[64 * 128];
  __shared__ char lp[4][16 * 128];

  // stage Q tile (rows q0..q0+63, 64 hd)
#pragma unroll
  for (int qq = 0; qq < 2; ++qq) {
    const int L = t * 8 + qq * 2048;
    const int r = L >> 6, c = L & 63;
    const int dst = r * 128 + ((c * 2) ^ ((r & 7) << 4));
    *(int4*)(lq + dst) =
        *(const int4*)(qh + ((size_t)bh * 2048 + q0 + r) * 64 + c);
  }
  __syncthreads();
  bf16x8 qf[2];
  {
    const int row = wv * 16 + (l & 15);
#pragma unroll
    for (int ks = 0; ks < 2; ++ks)
      qf[ks] = *(const bf16x8*)(lq + row * 128 +
                                ((ks * 64 + ((l >> 4) << 4)) ^ ((row & 7) << 4)));
  }
  float m_r[4], l_r[4];
  f32x4 acco[4];
#pragma unroll
  for (int rg = 0; rg < 4; ++rg) { m_r[rg] = -1e30f; l_r[rg] = 0.f; }
#pragma unroll
  for (int jf = 0; jf < 4; ++jf) acco[jf] = (f32x4){0.f, 0.f, 0.f, 0.f};

  for (int kv0 = 0; kv0 <= q0; kv0 += 64) {
#pragma unroll
    for (int qq = 0; qq < 2; ++qq) {
      const int L = t * 8 + qq * 2048;
      const int r = L >> 6, c = L & 63;
      const int dst = r * 128 + ((c * 2) ^ ((r & 7) << 4));
      *(int4*)(lk + dst) =
          *(const int4*)(kh + ((size_t)bh * 2048 + kv0 + r) * 64 + c);
      *(int4*)(lv + dst) =
          *(const int4*)(vth + ((size_t)bh * 64 + r) * 2048 + kv0 + c);
    }
    __syncthreads();
    // scores = Q @ K^T
    f32x4 sc[4];
#pragma unroll
    for (int jf = 0; jf < 4; ++jf) sc[jf] = (f32x4){0.f, 0.f, 0.f, 0.f};
#pragma unroll
    for (int ks = 0; ks < 2; ++ks) {
      const int kb = ks * 64 + ((l >> 4) << 4);
#pragma unroll
      for (int jf = 0; jf < 4; ++jf) {
        const int row = jf * 16 + (l & 15);
        bf16x8 kf = *(const bf16x8*)(lk + row * 128 + (kb ^ ((row & 7) << 4)));
        sc[jf] = __builtin_amdgcn_mfma_f32_16x16x32_bf16(qf[ks], kf, sc[jf], 0, 0, 0);
      }
    }
    // scale + causal mask (only diagonal block partially masked)
#pragma unroll
    for (int jf = 0; jf < 4; ++jf)
#pragma unroll
      for (int rg = 0; rg < 4; ++rg) {
        float v = sc[jf][rg] * 0.125f;
        if (kv0 == q0) {
          const int col = jf * 16 + (l & 15);
          const int rowq = wv * 16 + ((l >> 4) << 2) + rg;
          if (col > rowq) v = -1e30f;
        }
        sc[jf][rg] = v;
      }
    // row max across 64 cols: local over 4 frags, then 16-lane group reduce
    float tm[4];
#pragma unroll
    for (int rg = 0; rg < 4; ++rg)
      tm[rg] = fmaxf(fmaxf(sc[0][rg], sc[1][rg]), fmaxf(sc[2][rg], sc[3][rg]));
#pragma unroll
    for (int d = 1; d < 16; d <<= 1)
#pragma unroll
      for (int rg = 0; rg < 4; ++rg) tm[rg] = fmaxf(tm[rg], __shfl_xor(tm[rg], d));
    float esc[4], rs[4];
#pragma unroll
    for (int rg = 0; rg < 4; ++rg) {
      const float mn = fmaxf(m_r[rg], tm[rg]);
      esc[rg] = __expf(m_r[rg] - mn);
      m_r[rg] = mn;
      rs[rg] = 0.f;
    }
    unsigned short pu[4][4];
#pragma unroll
    for (int jf = 0; jf < 4; ++jf)
#pragma unroll
      for (int rg = 0; rg < 4; ++rg) {
        const float p = __expf(sc[jf][rg] - m_r[rg]);
        rs[rg] += p;
        pu[jf][rg] = f2bf(p);
      }
#pragma unroll
    for (int d = 1; d < 16; d <<= 1)
#pragma unroll
      for (int rg = 0; rg < 4; ++rg) rs[rg] += __shfl_xor(rs[rg], d);
#pragma unroll
    for (int rg = 0; rg < 4; ++rg) l_r[rg] = l_r[rg] * esc[rg] + rs[rg];
    // P -> per-wave LDS (bf16, swizzled)
#pragma unroll
    for (int jf = 0; jf < 4; ++jf)
#pragma unroll
      for (int rg = 0; rg < 4; ++rg) {
        const int pr = ((l >> 4) << 2) + rg;
        const int pc = jf * 16 + (l & 15);
        *(unsigned short*)(lp[wv] + pr * 128 + ((pc * 2) ^ ((pr & 7) << 4))) =
            pu[jf][rg];
      }
    __syncthreads();
    // rescale O, then O += P @ V
#pragma unroll
    for (int jf = 0; jf < 4; ++jf)
#pragma unroll
      for (int rg = 0; rg < 4; ++rg) acco[jf][rg] *= esc[rg];
    bf16x8 pf[2];
    {
      const int prow = l & 15;
#pragma unroll
      for (int ks = 0; ks < 2; ++ks)
        pf[ks] = *(const bf16x8*)(lp[wv] + prow * 128 +
                                  ((ks * 64 + ((l >> 4) << 4)) ^ ((prow & 7) << 4)));
    }
#pragma unroll
    for (int ks = 0; ks < 2; ++ks) {
      const int kb = ks * 64 + ((l >> 4) << 4);
#pragma unroll
      for (int jf = 0; jf < 4; ++jf) {
        const int row = jf * 16 + (l & 15);
        bf16x8 vf = *(const bf16x8*)(lv + row * 128 + (kb ^ ((row & 7) << 4)));
        acco[jf] = __builtin_amdgcn_mfma_f32_16x16x32_bf16(pf[ks], vf, acco[jf], 0, 0, 0);
      }
    }
    __syncthreads();
  }
  // epilogue: out[B,S,D] bf16
  const int b = bh >> 4, h = bh & 15;
#pragma unroll
  for (int jf = 0; jf < 4; ++jf)
#pragma unroll
    for (int rg = 0; rg < 4; ++rg) {
      const int rowl = ((l >> 4) << 2) + rg;
      const int qg = q0 + wv * 16 + rowl;
      const int n = h * 64 + jf * 16 + (l & 15);
      out[((size_t)(b * 2048 + qg)) * 1024 + n] = f2bf(acco[jf][rg] / l_r[rg]);
    }
}

extern "C" void kernel_launch(void* const* d_in, const int* in_sizes, int n_in,
                              void* d_out, int out_size, void* d_ws, size_t ws_size,
                              hipStream_t stream) {
  (void)in_sizes; (void)n_in; (void)out_size; (void)ws_size;
  const float* query = (const float*)d_in[0];
  const float* key = (const float*)d_in[1];
  const float* value = (const float*)d_in[2];
  const float* Wq = (const float*)d_in[4];
  const float* bq = (const float*)d_in[5];
  const float* Wk = (const float*)d_in[6];
  const float* bk = (const float*)d_in[7];
  const float* Wv = (const float*)d_in[8];
  const float* bv = (const float*)d_in[9];
  const float* Wo = (const float*)d_in[10];
  const float* bo = (const float*)d_in[11];

  char* ws = (char*)d_ws;
  const size_t SZ = (size_t)4 * 16 * 2048 * 64 * 2;  // 16 MiB per bf16 tensor
  unsigned short* qh = (unsigned short*)(ws);
  unsigned short* kh = (unsigned short*)(ws + SZ);
  unsigned short* vt = (unsigned short*)(ws + 2 * SZ);
  unsigned short* ao = (unsigned short*)(ws + 3 * SZ);

  dim3 gg(64, 8), bb(256);
  hipLaunchKernelGGL((gemm_k<0, 0>), gg, bb, 0, stream, (const void*)query, Wq, bq, (void*)qh);
  hipLaunchKernelGGL((gemm_k<0, 0>), gg, bb, 0, stream, (const void*)key, Wk, bk, (void*)kh);
  hipLaunchKernelGGL((gemm_k<0, 1>), gg, bb, 0, stream, (const void*)value, Wv, bv, (void*)vt);
  hipLaunchKernelGGL(attn_k, dim3(64, 32), bb, 0, stream, qh, kh, vt, ao);
  hipLaunchKernelGGL((gemm_k<1, 2>), gg, bb, 0, stream, (const void*)ao, Wo, bo, d_out);
}